// Round 10
// baseline (62.471 us; speedup 1.0000x reference)
//
#include <hip/hip_runtime.h>

// MOLGCirculantLinear: software-pipelined fused kernel, R9.
// x[512][1024] f32, w[128][128][8] f32, scale[64][8] f32.
// d_out = out[512][1024] ++ phase[512][128][128][8].
//
// One wave per (b, 4 consecutive gy). Lane i owns (gxs=i>>1, kq=i&1).
// R9 vs R8: (1) w prefetch = 3-deep rotating 2xf32x4 buffer over flattened
// 16-step (j,it) loop, distance 2 (~240cy) -> ~40 fewer VGPR, aiming for
// <=128 VGPR = 4 waves/SIMD residency; (2) reduce tail butterflies are
// stage-major (16 independent shuffles per stage pipeline the ds latency).
// Conv/store core identical to R7/R8 (absmax 1.0 preserved).

#define NB   512
#define NGY  128
#define NGX  128
#define NK   8

typedef float f32x4 __attribute__((ext_vector_type(4)));

__global__ __launch_bounds__(256, 2) void molg_pipe(
    const float* __restrict__ x,
    const float* __restrict__ w,
    const float* __restrict__ scale,
    float* __restrict__ d_out)
{
    const int lane = threadIdx.x & 63;
    const int wv   = threadIdx.x >> 6;        // 0..3
    const int b    = blockIdx.x >> 3;         // 512 b
    const int gy0  = (blockIdx.x & 7) * 16 + wv * 4;

    const int gxs = lane >> 1;                // 0..31
    const int kq  = lane & 1;                 // k-half

    float* out   = d_out;
    float* phase = d_out + (size_t)NB * NGY * NK;

    const float c0 = 0.02403f, c1 = -0.2699f, c2 = 1.17f,
                c3 = -2.454f,  c4 = 2.523f,  c5 = -0.08003f;

    // ---- per-wave preload: x^2 rotated by 4*kq, for 4 gx positions ----
    float y[4][NK];
#pragma unroll
    for (int it = 0; it < 4; ++it) {
        const int gx = 32 * it + gxs;
        const f32x4* xp = reinterpret_cast<const f32x4*>(x + (size_t)b * 1024 + gx * NK);
        f32x4 a = xp[0], c = xp[1];
        float t[NK] = {a[0]*a[0], a[1]*a[1], a[2]*a[2], a[3]*a[3],
                       c[0]*c[0], c[1]*c[1], c[2]*c[2], c[3]*c[3]};
#pragma unroll
        for (int q = 0; q < NK; ++q)
            y[it][q] = kq ? t[(q + 4) & 7] : t[q];
    }

    // scale: gx&63 = gxs (it even) or gxs+32 (it odd)
    const f32x4 sve = *reinterpret_cast<const f32x4*>(scale + (size_t)gxs * NK + 4 * kq);
    const f32x4 svo = *reinterpret_cast<const f32x4*>(scale + (size_t)(gxs + 32) * NK + 4 * kq);

    // ---- w: 3-deep rotating prefetch over flattened steps s=(j<<2)|it ----
    const float* wbase = w + ((size_t)gy0 * NGX + gxs) * NK;
    f32x4 wb[3][2];
#pragma unroll
    for (int s = 0; s < 2; ++s) {
        const f32x4* p = reinterpret_cast<const f32x4*>(
            wbase + (((s >> 2) * NGX + (s & 3) * 32)) * NK);
        wb[s][0] = p[0];
        wb[s][1] = p[1];
    }

    float acc[4][4];
#pragma unroll
    for (int j = 0; j < 4; ++j)
#pragma unroll
        for (int q = 0; q < 4; ++q) acc[j][q] = 0.f;

    // phase rows gy0..gy0+3 are contiguous: base + j*256 + it*64 (f32x4 units)
    f32x4* pbase4 = reinterpret_cast<f32x4*>(
        phase + (((size_t)b * NGY + gy0) * NGX) * NK);

#pragma unroll
    for (int s = 0; s < 16; ++s) {
        if (s < 14) {   // prefetch step s+2 (distance 2 ~ 240 cy)
            const int t = s + 2;
            const f32x4* p = reinterpret_cast<const f32x4*>(
                wbase + (((t >> 2) * NGX + (t & 3) * 32)) * NK);
            wb[t % 3][0] = p[0];
            wb[t % 3][1] = p[1];
        }
        const int j = s >> 2, it = s & 3;
        const f32x4 wa = wb[s % 3][0], wc = wb[s % 3][1];
        const float wf[NK] = {wa[0], wa[1], wa[2], wa[3], wc[0], wc[1], wc[2], wc[3]};

        float xr[4];
#pragma unroll
        for (int n = 0; n < 4; ++n) {
            float acc_s = 0.f;
#pragma unroll
            for (int m = 0; m < NK; ++m)
                acc_s = fmaf(wf[m], y[it][(n - m) & 7], acc_s);
            xr[n] = acc_s;
        }

        // dense 1KB line-aligned burst: lane i -> byte 16*i (nontemporal)
        f32x4 q = {xr[0], xr[1], xr[2], xr[3]};
        __builtin_nontemporal_store(q, pbase4 + j * 256 + it * 64 + lane);

        const f32x4 sv = (it & 1) ? svo : sve;
#pragma unroll
        for (int n = 0; n < 4; ++n) {
            float v = xr[n];
            float p = fmaf(c0, v, c1);
            p = fmaf(p, v, c2);
            p = fmaf(p, v, c3);
            p = fmaf(p, v, c4);
            p = fmaf(p, v, c5);
            p = fminf(fmaxf(p, 0.f), 1.f);
            acc[j][n] = fmaf(p, sv[n], acc[j][n]);
        }
    }

    // ---- tail: stage-major butterflies (16 independent shuffles per stage) ----
#pragma unroll
    for (int off = 2; off < 64; off <<= 1)
#pragma unroll
        for (int j = 0; j < 4; ++j)
#pragma unroll
            for (int n = 0; n < 4; ++n)
                acc[j][n] += __shfl_xor(acc[j][n], off, 64);

#pragma unroll
    for (int j = 0; j < 4; ++j) {
        if (lane < 2) {   // lane0: k0..3, lane1: k4..7
            f32x4 v = {fmaf(2.f, acc[j][0], -128.f), fmaf(2.f, acc[j][1], -128.f),
                       fmaf(2.f, acc[j][2], -128.f), fmaf(2.f, acc[j][3], -128.f)};
            *(reinterpret_cast<f32x4*>(out + (size_t)b * 1024 + (gy0 + j) * NK) + lane) = v;
        }
    }
}

extern "C" void kernel_launch(void* const* d_in, const int* in_sizes, int n_in,
                              void* d_out, int out_size, void* d_ws, size_t ws_size,
                              hipStream_t stream) {
    const float* x     = (const float*)d_in[0];
    const float* w     = (const float*)d_in[1];
    const float* scale = (const float*)d_in[2];
    float* out = (float*)d_out;

    dim3 grid(4096);    // 512 b x 8 gy-groups; one wave per (b, 4 gy)
    dim3 block(256);
    hipLaunchKernelGGL(molg_pipe, grid, block, 0, stream, x, w, scale, out);
}

// Round 11
// 52.707 us; speedup vs baseline: 1.1852x; 1.1852x over previous
//
#include <hip/hip_runtime.h>

// MOLGCirculantLinear R10: R8's pipeline + w shared across b via LDS.
// x[512][1024] f32, w[128][128][8] f32, scale[64][8] f32.
// d_out = out[512][1024] ++ phase[512][128][128][8].
//
// Block = 4 waves = 4 different b, same 4-gy strip. w rows gy0..gy0+3 (16KB)
// staged in LDS once (coalesced, one barrier); each wave then runs the R8
// per-step loop (lane: gxs=lane>>1, kq=lane&1; 16 steps (j,it)) with w read
// from LDS -> zero global loads in the main loop, dense 1KB nt store bursts,
// stage-major butterfly tail. Cuts w L2 re-reads 268MB -> 67MB (TCC relief).

#define NB   512
#define NGY  128
#define NGX  128
#define NK   8

typedef float f32x4 __attribute__((ext_vector_type(4)));

__global__ __launch_bounds__(256, 4) void molg_lds(
    const float* __restrict__ x,
    const float* __restrict__ w,
    const float* __restrict__ scale,
    float* __restrict__ d_out)
{
    __shared__ f32x4 lw[1024];               // 4 gy rows x 1024 floats = 16KB

    const int tid  = threadIdx.x;
    const int lane = tid & 63;
    const int wv   = tid >> 6;               // 0..3 -> which b
    const int bg   = blockIdx.x >> 5;        // 0..127 b-group
    const int gs   = blockIdx.x & 31;        // 0..31 gy-strip
    const int b    = bg * 4 + wv;
    const int gy0  = gs * 4;

    const int gxs = lane >> 1;               // 0..31
    const int kq  = lane & 1;                // k-half

    float* out   = d_out;
    float* phase = d_out + (size_t)NB * NGY * NK;

    const float c0 = 0.02403f, c1 = -0.2699f, c2 = 1.17f,
                c3 = -2.454f,  c4 = 2.523f,  c5 = -0.08003f;

    // ---- stage w rows gy0..gy0+3 into LDS (4096 floats, coalesced) ----
    {
        const f32x4* wsrc = reinterpret_cast<const f32x4*>(w + (size_t)gy0 * NGX * NK);
#pragma unroll
        for (int u = 0; u < 4; ++u)
            lw[tid + 256 * u] = wsrc[tid + 256 * u];
    }

    // ---- per-wave preload: x^2 rotated by 4*kq, for 4 gx positions ----
    float y[4][NK];
#pragma unroll
    for (int it = 0; it < 4; ++it) {
        const int gx = 32 * it + gxs;
        const f32x4* xp = reinterpret_cast<const f32x4*>(x + (size_t)b * 1024 + gx * NK);
        f32x4 a = xp[0], c = xp[1];
        float t[NK] = {a[0]*a[0], a[1]*a[1], a[2]*a[2], a[3]*a[3],
                       c[0]*c[0], c[1]*c[1], c[2]*c[2], c[3]*c[3]};
#pragma unroll
        for (int q = 0; q < NK; ++q)
            y[it][q] = kq ? t[(q + 4) & 7] : t[q];
    }

    // scale: gx&63 = gxs (it even) or gxs+32 (it odd)
    const f32x4 sve = *reinterpret_cast<const f32x4*>(scale + (size_t)gxs * NK + 4 * kq);
    const f32x4 svo = *reinterpret_cast<const f32x4*>(scale + (size_t)(gxs + 32) * NK + 4 * kq);

    float acc[4][4];
#pragma unroll
    for (int j = 0; j < 4; ++j)
#pragma unroll
        for (int q = 0; q < 4; ++q) acc[j][q] = 0.f;

    __syncthreads();

    // phase rows gy0..gy0+3 for this wave's b: base + j*256 + it*64 (f32x4)
    f32x4* pbase4 = reinterpret_cast<f32x4*>(
        phase + (((size_t)b * NGY + gy0) * NGX) * NK);

#pragma unroll
    for (int s = 0; s < 16; ++s) {
        const int j = s >> 2, it = s & 3;

        // w from LDS: both lanes of a pair read the same 32B (2-way bcast, free)
        const f32x4 wa = lw[j * 256 + it * 64 + gxs * 2];
        const f32x4 wc = lw[j * 256 + it * 64 + gxs * 2 + 1];
        const float wf[NK] = {wa[0], wa[1], wa[2], wa[3], wc[0], wc[1], wc[2], wc[3]};

        float xr[4];
#pragma unroll
        for (int n = 0; n < 4; ++n) {
            float s_ = 0.f;
#pragma unroll
            for (int m = 0; m < NK; ++m)
                s_ = fmaf(wf[m], y[it][(n - m) & 7], s_);
            xr[n] = s_;
        }

        // dense 1KB line-aligned burst: lane i -> byte 16*i (nontemporal)
        f32x4 q = {xr[0], xr[1], xr[2], xr[3]};
        __builtin_nontemporal_store(q, pbase4 + j * 256 + it * 64 + lane);

        const f32x4 sv = (it & 1) ? svo : sve;
#pragma unroll
        for (int n = 0; n < 4; ++n) {
            float v = xr[n];
            float p = fmaf(c0, v, c1);
            p = fmaf(p, v, c2);
            p = fmaf(p, v, c3);
            p = fmaf(p, v, c4);
            p = fmaf(p, v, c5);
            p = fminf(fmaxf(p, 0.f), 1.f);
            acc[j][n] = fmaf(p, sv[n], acc[j][n]);
        }
    }

    // ---- tail: stage-major butterflies (16 independent shuffles per stage) ----
#pragma unroll
    for (int off = 2; off < 64; off <<= 1)
#pragma unroll
        for (int j = 0; j < 4; ++j)
#pragma unroll
            for (int n = 0; n < 4; ++n)
                acc[j][n] += __shfl_xor(acc[j][n], off, 64);

#pragma unroll
    for (int j = 0; j < 4; ++j) {
        if (lane < 2) {   // lane0: k0..3, lane1: k4..7
            f32x4 v = {fmaf(2.f, acc[j][0], -128.f), fmaf(2.f, acc[j][1], -128.f),
                       fmaf(2.f, acc[j][2], -128.f), fmaf(2.f, acc[j][3], -128.f)};
            *(reinterpret_cast<f32x4*>(out + (size_t)b * 1024 + (gy0 + j) * NK) + lane) = v;
        }
    }
}

extern "C" void kernel_launch(void* const* d_in, const int* in_sizes, int n_in,
                              void* d_out, int out_size, void* d_ws, size_t ws_size,
                              hipStream_t stream) {
    const float* x     = (const float*)d_in[0];
    const float* w     = (const float*)d_in[1];
    const float* scale = (const float*)d_in[2];
    float* out = (float*)d_out;

    dim3 grid(4096);    // 128 b-groups x 32 gy-strips; 4 waves = 4 b per block
    dim3 block(256);
    hipLaunchKernelGGL(molg_lds, grid, block, 0, stream, x, w, scale, out);
}